// Round 1
// baseline (90114.410 us; speedup 1.0000x reference)
//
#include <hip/hip_runtime.h>
#include <cstddef>

// CubicRNN on MI355X — round 1: correct fp32 direct-conv implementation.
// B=4, T=10, C=1, H=W=64, HC=32, S=3 cells, L=3 layers, kx=3, kz=5, ky=1.
// 18 steps (idx=2..19), out_len=10 (hard-coded; shapes fixed by harness).

#define HW 4096   // 64*64
#define NB 4      // batch

__device__ __forceinline__ float sigm(float x) { return 1.f / (1.f + expf(-x)); }

__global__ __launch_bounds__(256) void zero_kernel(float* __restrict__ p, size_t n) {
    size_t i = (size_t)blockIdx.x * blockDim.x + threadIdx.x;
    size_t st = (size_t)gridDim.x * blockDim.x;
    for (; i < n; i += st) p[i] = 0.f;
}

// Fused gate conv: computes gates_x = conv3x3(cat) + bx and
// gates_z = conv5x5(cat) + bz, cat = [x(CIN_X ch), hx(32), hz(32)].
// One block: one batch, one 16x16 pixel tile, 16 of 128 output channels.
// grid = (16 tiles, 8 co-groups, 4 batch), block = 256 (1 thread / pixel).
template <int CIN_X>
__global__ __launch_bounds__(256) void gate_conv(
    const float* __restrict__ x, int xbstride,
    const float* __restrict__ sx,  // src x-state [B,64,H,W]: h=ch 0..31, c=ch 32..63
    const float* __restrict__ sz,  // z-state, same layout
    const float* __restrict__ wx, const float* __restrict__ bx,
    const float* __restrict__ wz, const float* __restrict__ bz,
    float* __restrict__ gx, float* __restrict__ gz)
{
    constexpr int CIN = CIN_X + 64;
    const int tile = blockIdx.x;
    const int cog  = blockIdx.y;
    const int b    = blockIdx.z;
    const int ty = threadIdx.x >> 4, tx = threadIdx.x & 15;
    const int y0 = (tile >> 2) << 4, x0 = (tile & 3) << 4;
    const int co0 = cog << 4;

    __shared__ float sm[400];  // 20x20 halo tile (pad 2 for 5x5)

    float ax[16], az[16];
#pragma unroll
    for (int i = 0; i < 16; i++) { ax[i] = bx[co0 + i]; az[i] = bz[co0 + i]; }

    for (int c = 0; c < CIN; ++c) {
        const float* src;
        if (c < CIN_X)            src = x  + (size_t)b * xbstride + (size_t)c * HW;
        else if (c < CIN_X + 32)  src = sx + ((size_t)b * 64 + (c - CIN_X)) * HW;
        else                      src = sz + ((size_t)b * 64 + (c - CIN_X - 32)) * HW;
        __syncthreads();  // protect previous iteration's tile reads
        for (int j = threadIdx.x; j < 400; j += 256) {
            int r = j / 20, q = j % 20;
            int gy = y0 + r - 2, gq = x0 + q - 2;
            float v = 0.f;
            if (gy >= 0 && gy < 64 && gq >= 0 && gq < 64) v = src[gy * 64 + gq];
            sm[j] = v;
        }
        __syncthreads();
        float v[25];
#pragma unroll
        for (int i = 0; i < 25; i++) v[i] = sm[(ty + i / 5) * 20 + tx + (i % 5)];
        const float* wzc = wz + ((size_t)co0 * CIN + c) * 25;
        const float* wxc = wx + ((size_t)co0 * CIN + c) * 9;
#pragma unroll
        for (int co = 0; co < 16; ++co) {
            const float* wzp = wzc + (size_t)co * CIN * 25;
            float s = 0.f;
#pragma unroll
            for (int i = 0; i < 25; i++) s += v[i] * wzp[i];
            az[co] += s;
            const float* wxp = wxc + (size_t)co * CIN * 9;
            float s2 = 0.f;
#pragma unroll
            for (int r = 0; r < 3; r++)
#pragma unroll
                for (int q = 0; q < 3; q++) s2 += v[(r + 1) * 5 + q + 1] * wxp[r * 3 + q];
            ax[co] += s2;
        }
    }
    size_t base = ((size_t)b * 128 + co0) * HW + (size_t)(y0 + ty) * 64 + (x0 + tx);
#pragma unroll
    for (int co = 0; co < 16; ++co) {
        gx[base + (size_t)co * HW] = ax[co];
        gz[base + (size_t)co * HW] = az[co];
    }
}

// LSTM gating for both branches. N = B*32*HW threads.
__global__ __launch_bounds__(256) void gating(
    const float* __restrict__ gx, const float* __restrict__ gz,
    const float* __restrict__ srcx, const float* __restrict__ srcz,
    float* __restrict__ dstx, float* __restrict__ dstz)
{
    int n = blockIdx.x * 256 + threadIdx.x;
    int p = n & (HW - 1); int ch = (n >> 12) & 31; int b = n >> 17;
    size_t gb = ((size_t)b * 128 + ch) * HW + p;
    size_t hb = ((size_t)b * 64 + ch) * HW + p;
    size_t cb = hb + (size_t)32 * HW;
    {
        float i = gx[gb], f = gx[gb + (size_t)32 * HW], g = gx[gb + (size_t)64 * HW],
              o = gx[gb + (size_t)96 * HW];
        float c = srcx[cb];
        float cn = sigm(f + 0.01f) * c + sigm(i) * tanhf(g);
        dstx[cb] = cn;
        dstx[hb] = sigm(o) * tanhf(cn);
    }
    {
        float i = gz[gb], f = gz[gb + (size_t)32 * HW], g = gz[gb + (size_t)64 * HW],
              o = gz[gb + (size_t)96 * HW];
        float c = srcz[cb];
        float cn = sigm(f + 0.01f) * c + sigm(i) * tanhf(g);
        dstz[cb] = cn;
        dstz[hb] = sigm(o) * tanhf(cn);
    }
}

// y = conv1x1([hx2;hz2], wy) + by : 64 -> 32 channels. N = B*32*HW threads.
__global__ __launch_bounds__(256) void yconv(
    const float* __restrict__ hx, const float* __restrict__ hz,
    const float* __restrict__ wy, const float* __restrict__ by,
    float* __restrict__ y)
{
    int n = blockIdx.x * 256 + threadIdx.x;
    int p = n & (HW - 1); int co = (n >> 12) & 31; int b = n >> 17;
    const float* hxp = hx + (size_t)b * 64 * HW + p;
    const float* hzp = hz + (size_t)b * 64 * HW + p;
    const float* w = wy + co * 64;
    float acc = by[co];
#pragma unroll
    for (int ci = 0; ci < 32; ++ci) acc += w[ci] * hxp[(size_t)ci * HW];
#pragma unroll
    for (int ci = 0; ci < 32; ++ci) acc += w[32 + ci] * hzp[(size_t)ci * HW];
    y[((size_t)b * 32 + co) * HW + p] = acc;
}

// pred = conv1x1(y, w_last), 32 -> 1, no bias. N = B*HW threads.
__global__ __launch_bounds__(256) void predconv(
    const float* __restrict__ y, const float* __restrict__ wl, float* __restrict__ pred)
{
    int n = blockIdx.x * 256 + threadIdx.x;
    int p = n & (HW - 1); int b = n >> 12;
    const float* yp = y + (size_t)b * 32 * HW + p;
    float acc = 0.f;
#pragma unroll
    for (int ci = 0; ci < 32; ++ci) acc += wl[ci] * yp[(size_t)ci * HW];
    pred[n] = acc;
}

// out[b, ti, 0, h, w] = preds[8 + ti][b, h, w]  (last 10 of 18 steps)
__global__ __launch_bounds__(256) void emit(
    const float* __restrict__ preds8, float* __restrict__ out)
{
    int n = blockIdx.x * 256 + threadIdx.x;  // 163840
    int p = n & (HW - 1); int ti = (n >> 12) % 10; int b = n / (10 * HW);
    out[n] = preds8[(size_t)ti * (NB * HW) + (size_t)b * HW + p];
}

extern "C" void kernel_launch(void* const* d_in, const int* in_sizes, int n_in,
                              void* d_out, int out_size, void* d_ws, size_t ws_size,
                              hipStream_t stream)
{
    const float* input_seq = (const float*)d_in[0];
    const float* w_x0 = (const float*)d_in[1];
    const float* b_x0 = (const float*)d_in[2];
    const float* w_z0 = (const float*)d_in[3];
    const float* b_z0 = (const float*)d_in[4];
    const float* w_y0 = (const float*)d_in[5];
    const float* b_y0 = (const float*)d_in[6];
    const float* w_x1 = (const float*)d_in[7];
    const float* b_x1 = (const float*)d_in[8];
    const float* w_z1 = (const float*)d_in[9];
    const float* b_z1 = (const float*)d_in[10];
    const float* b_y1 = (const float*)d_in[12];
    const float* w_y1 = (const float*)d_in[11];
    const float* w_last = (const float*)d_in[13];

    float* ws = (float*)d_ws;
    const size_t ST = (size_t)NB * 64 * HW;   // state buffer: 1,048,576 floats
    const size_t YS = (size_t)NB * 32 * HW;   // y buffer
    const size_t G  = (size_t)NB * 128 * HW;  // gates buffer
    const size_t P  = (size_t)NB * HW;        // pred buffer

    size_t off = 0;
    float *SX0[3], *SX1[3], *SZ[3];
    for (int l = 0; l < 3; l++) { SX0[l] = ws + off; off += ST; }
    for (int l = 0; l < 3; l++) { SX1[l] = ws + off; off += ST; }
    for (int l = 0; l < 3; l++) { SZ[l]  = ws + off; off += ST; }
    float* DUMMY = ws + off; off += ST;      // dead sx[l][2] writes land here
    float *ysA[3], *ysB[3];
    for (int s = 0; s < 3; s++) { ysA[s] = ws + off; off += YS; }
    for (int s = 0; s < 3; s++) { ysB[s] = ws + off; off += YS; }
    float* gxbuf = ws + off; off += G;
    float* gzbuf = ws + off; off += G;
    float* preds = ws + off; off += 18 * P;
    (void)ws_size; (void)in_sizes; (void)n_in; (void)out_size;

    // zero persistent states (SX0, SX1, SZ are the first 9*ST floats)
    zero_kernel<<<2048, 256, 0, stream>>>(ws, 9 * ST);

    for (int step = 0; step < 18; ++step) {
        int idx = step + 2;
        // window = [cand_{idx-2}, cand_{idx-1}, cand_idx]
        const float* xw[3]; int xstr[3];
        for (int s = 0; s < 3; s++) {
            int j = idx - 2 + s;
            if (j < 10) { xw[s] = input_seq + (size_t)j * HW; xstr[s] = 10 * HW; }
            else        { xw[s] = preds + (size_t)(j - 3) * P; xstr[s] = HW; }
        }
        for (int l = 0; l < 3; l++) {
            for (int s = 0; s < 3; s++) {
                const float *wx, *bx, *wz, *bz, *wy, *by;
                if (l == 0) {
                    wx = w_x0 + (size_t)s * 128 * 65 * 9;  bx = b_x0 + s * 128;
                    wz = w_z0 + (size_t)s * 128 * 65 * 25; bz = b_z0 + s * 128;
                    wy = w_y0 + (size_t)s * 32 * 64;       by = b_y0 + s * 32;
                } else {
                    int li = (l - 1) * 3 + s;
                    wx = w_x1 + (size_t)li * 128 * 96 * 9;  bx = b_x1 + li * 128;
                    wz = w_z1 + (size_t)li * 128 * 96 * 25; bz = b_z1 + li * 128;
                    wy = w_y1 + (size_t)li * 32 * 64;       by = b_y1 + li * 32;
                }
                // s==0 reads/writes SX0 (prev step's state); s==1 reads fresh SX0,
                // writes SX1; s==2 reads fresh SX1, writes DUMMY (never read).
                const float* srcx = (s == 2) ? SX1[l] : SX0[l];
                float* dstx = (s == 0) ? SX0[l] : (s == 1 ? SX1[l] : DUMMY);
                const float* xin; int xs_;
                if (l == 0) { xin = xw[s]; xs_ = xstr[s]; }
                else        { xin = (l == 1 ? ysA[s] : ysB[s]); xs_ = 32 * HW; }
                float* yout = (l == 1) ? ysB[s] : ysA[s];

                dim3 g1(16, 8, 4);
                if (l == 0)
                    gate_conv<1><<<g1, 256, 0, stream>>>(xin, xs_, srcx, SZ[l],
                                                         wx, bx, wz, bz, gxbuf, gzbuf);
                else
                    gate_conv<32><<<g1, 256, 0, stream>>>(xin, xs_, srcx, SZ[l],
                                                          wx, bx, wz, bz, gxbuf, gzbuf);
                gating<<<(NB * 32 * HW) / 256, 256, 0, stream>>>(gxbuf, gzbuf, srcx, SZ[l],
                                                                 dstx, SZ[l]);
                yconv<<<(NB * 32 * HW) / 256, 256, 0, stream>>>(dstx, SZ[l], wy, by, yout);
            }
        }
        predconv<<<(NB * HW) / 256, 256, 0, stream>>>(ysA[2], w_last,
                                                       preds + (size_t)step * P);
    }
    emit<<<(NB * 10 * HW) / 256, 256, 0, stream>>>(preds + 8 * P, (float*)d_out);
}

// Round 2
// 13299.828 us; speedup vs baseline: 6.7756x; 6.7756x over previous
//
#include <hip/hip_runtime.h>
#include <cstddef>
#include <cstdint>

// CubicRNN MI355X — round 2: split-bf16 MFMA implicit conv, fused LSTM epilogue.
// B=4, T=10, C=1, H=W=64, HC=32, S=3, L=3, kx=3, kz=5, ky=1, 18 steps.
// Every activation/weight is a bf16 (hi,lo) pair; conv = AhBh + AlBh + AhBl
// via v_mfma_f32_16x16x32_bf16 (dropped AlBl term ~2^-18 relative).

typedef __attribute__((ext_vector_type(8))) short bf16x8;
typedef __attribute__((ext_vector_type(4))) float f32x4;

#define HW 4096
#define NB 4

__device__ __forceinline__ float sigm(float x){ return 1.f/(1.f+expf(-x)); }
__device__ __forceinline__ unsigned short bf16rn(float x){
  unsigned int u = __float_as_uint(x);
  u = (u + 0x7FFFu + ((u>>16)&1u)) >> 16;
  return (unsigned short)u;
}
__device__ __forceinline__ float bf2f(unsigned short h){ return __uint_as_float(((unsigned int)h)<<16); }

__global__ __launch_bounds__(256) void zero4(uint4* __restrict__ p, size_t n){
  size_t i = (size_t)blockIdx.x*blockDim.x + threadIdx.x;
  size_t st = (size_t)gridDim.x*blockDim.x;
  uint4 z = make_uint4(0u,0u,0u,0u);
  for (; i < n; i += st) p[i] = z;
}

// Pack conv weights (fp32 OIHW) -> [tap][kc(3)][co(128)][k(32)] bf16 hi/lo,
// with cat channels remapped into uniform 96 (layer0: ci0->k0, ci1..64->k32..95).
__global__ __launch_bounds__(256) void pack_w(const float* __restrict__ src,
    unsigned short* __restrict__ dh, unsigned short* __restrict__ dl,
    int taps, int cin, int l0){
  int idx = blockIdx.x*256 + threadIdx.x;
  int k = idx & 31, co = (idx>>5) & 127, rest = idx >> 12;
  int tap = rest/3, kc = rest - tap*3;
  int p = kc*32 + k;
  int ci = l0 ? ((p==0) ? 0 : ((p>=32) ? p-31 : -1)) : p;
  float wv = 0.f;
  if (ci >= 0 && ci < cin) wv = src[((size_t)co*cin + ci)*taps + tap];
  unsigned short h = bf16rn(wv);
  unsigned short l = bf16rn(wv - bf2f(h));
  dh[idx] = h; dl[idx] = l;
}

// Write frame (or fed-back pred) into ch0 (hi) / ch96 (lo) of layer-0 cat bufs.
__global__ __launch_bounds__(256) void frame_fill(const float* __restrict__ inseq,
    const float* __restrict__ predbuf, int step,
    unsigned short* __restrict__ c0, unsigned short* __restrict__ c1,
    unsigned short* __restrict__ c2){
  int s = blockIdx.y;
  unsigned short* dst = (s==0) ? c0 : ((s==1) ? c1 : c2);
  int i = blockIdx.x*256 + threadIdx.x;          // b*4096 + px
  int b = i >> 12, px = i & 4095;
  int j = step + s;
  float v = (j < 10) ? inseq[((size_t)b*10 + j)*HW + px]
                     : predbuf[(size_t)(j-3)*(NB*HW) + (size_t)b*HW + px];
  unsigned short h = bf16rn(v);
  unsigned short l = bf16rn(v - bf2f(h));
  size_t base = (size_t)i * 192;
  dst[base] = h; dst[base + 96] = l;
}

struct CellArgs {
  const unsigned short* cat_in;                  // [B][4096][192] bf16 hi[96],lo[96]
  const unsigned short *wxh, *wxl, *wzh, *wzl;   // packed weights
  const float *bx, *bz;                          // [128]
  const float *cx_src; float *cx_dst;            // [B][4096][32] fp32 (dst may be null)
  float *cz;                                     // in-place
  unsigned short *hx_dst0, *hx_dst1, *hz_dst;    // cat bases (null = skip)
  const float *wy, *by;                          // [32][64],[32] (wy null = skip yconv)
  unsigned short *y_dst;                         // cat base ch0 (null = skip)
  const float *wl;                               // [32]; non-null = pred mode
  float *pred_out;                               // predbuf slot [B][4096]
  float *final_out;                              // d_out + ti*4096 (b-stride 40960) or null
};

union SM {
  unsigned short A[2][12*12*104];                // halo tile hi/lo, ch stride 104
  struct { float gates[128*65]; float hbuf[64*64]; float ybuf[64*33]; } ep;
};

__global__ __launch_bounds__(512, 2) void cell_kernel(CellArgs a){
  __shared__ SM sm;
  const int tid = threadIdx.x;
  const int b = blockIdx.y;
  const int reg = blockIdx.x;
  const int R0 = (reg >> 3) << 3, C0 = (reg & 7) << 3;   // 8x8 pixel region

  // ---- phase 1: stage halo (12x12 px x 96ch, hi+lo) into LDS ----
  for (int j = tid; j < 144*24; j += 512) {
    int px = j/24, part = j - px*24;
    int hr = px/12, hc = px - hr*12;
    int gy = R0 + hr - 2, gx = C0 + hc - 2;
    int hl = (part >= 12) ? 1 : 0;
    int p8 = (part - hl*12)*8;
    uint4 v = make_uint4(0u,0u,0u,0u);
    if (gy >= 0 && gy < 64 && gx >= 0 && gx < 64) {
      const unsigned short* src = a.cat_in + ((size_t)(b*4096 + gy*64 + gx))*192 + hl*96 + p8;
      v = *reinterpret_cast<const uint4*>(src);
    }
    *reinterpret_cast<uint4*>(&sm.A[hl][px*104 + p8]) = v;
  }
  __syncthreads();

  // ---- phase 2: conv (each wave: 16 co of gx AND 16 co of gz, 4 M-tiles) ----
  const int w = tid >> 6, lane = tid & 63, q = lane >> 4, n16 = lane & 15;
  const int mrow = n16 >> 3, mcol = n16 & 7;
  const int co = (w << 4) + n16;                 // 0..127
  const int kq = q*8;
  const int wb = co*32 + kq;                     // per-lane weight offset

  f32x4 zf = {0.f,0.f,0.f,0.f};
  f32x4 accx[4], accz[4];
#pragma unroll
  for (int t = 0; t < 4; ++t) { accx[t] = zf; accz[t] = zf; }

  bf16x8 nBzh = *reinterpret_cast<const bf16x8*>(a.wzh + wb);
  bf16x8 nBzl = *reinterpret_cast<const bf16x8*>(a.wzl + wb);
  bf16x8 nBxh = nBzh, nBxl = nBzl;               // dummy (tap0 not inner)

#pragma unroll 1
  for (int kc = 0; kc < 3; ++kc) {
#pragma unroll 1
    for (int tap = 0; tap < 25; ++tap) {
      int ky = tap/5, kx = tap - ky*5;
      bool inner = (ky >= 1 && ky <= 3 && kx >= 1 && kx <= 3);
      bf16x8 cBzh = nBzh, cBzl = nBzl, cBxh = nBxh, cBxl = nBxl;
      // prefetch next tap's B fragments (global, depth-1)
      int ntap = tap + 1, nkc = kc;
      if (ntap == 25) { ntap = 0; nkc = (kc == 2) ? 0 : kc + 1; }
      int nky = ntap/5, nkx = ntap - nky*5;
      {
        int zoff = (ntap*3 + nkc)*4096 + wb;
        nBzh = *reinterpret_cast<const bf16x8*>(a.wzh + zoff);
        nBzl = *reinterpret_cast<const bf16x8*>(a.wzl + zoff);
        if (nky >= 1 && nky <= 3 && nkx >= 1 && nkx <= 3) {
          int xoff = (((nky-1)*3 + (nkx-1))*3 + nkc)*4096 + wb;
          nBxh = *reinterpret_cast<const bf16x8*>(a.wxh + xoff);
          nBxl = *reinterpret_cast<const bf16x8*>(a.wxl + xoff);
        }
      }
      // A fragments from LDS: A[m=lane&15][k=q*8+j]
      int abase = ((mrow + ky)*12 + mcol + kx)*104 + kc*32 + kq;
      bf16x8 Ah[4], Al[4];
#pragma unroll
      for (int t = 0; t < 4; ++t) {
        Ah[t] = *reinterpret_cast<const bf16x8*>(&sm.A[0][abase + t*2496]);
        Al[t] = *reinterpret_cast<const bf16x8*>(&sm.A[1][abase + t*2496]);
      }
#pragma unroll
      for (int t = 0; t < 4; ++t) accz[t] = __builtin_amdgcn_mfma_f32_16x16x32_bf16(Ah[t], cBzh, accz[t], 0,0,0);
#pragma unroll
      for (int t = 0; t < 4; ++t) accz[t] = __builtin_amdgcn_mfma_f32_16x16x32_bf16(Al[t], cBzh, accz[t], 0,0,0);
#pragma unroll
      for (int t = 0; t < 4; ++t) accz[t] = __builtin_amdgcn_mfma_f32_16x16x32_bf16(Ah[t], cBzl, accz[t], 0,0,0);
      if (inner) {
#pragma unroll
        for (int t = 0; t < 4; ++t) accx[t] = __builtin_amdgcn_mfma_f32_16x16x32_bf16(Ah[t], cBxh, accx[t], 0,0,0);
#pragma unroll
        for (int t = 0; t < 4; ++t) accx[t] = __builtin_amdgcn_mfma_f32_16x16x32_bf16(Al[t], cBxh, accx[t], 0,0,0);
#pragma unroll
        for (int t = 0; t < 4; ++t) accx[t] = __builtin_amdgcn_mfma_f32_16x16x32_bf16(Ah[t], cBxl, accx[t], 0,0,0);
      }
    }
  }
  __syncthreads();   // conv done everywhere; safe to reuse LDS

  // ---- phase 3: branch-X gates -> LDS -> gating ----
#pragma unroll
  for (int t = 0; t < 4; ++t)
#pragma unroll
    for (int r = 0; r < 4; ++r) {
      int m = q*4 + r;
      int px = (2*t + (m >> 3))*8 + (m & 7);
      sm.ep.gates[co*65 + px] = accx[t][r];
    }
  __syncthreads();
#pragma unroll
  for (int i = 0; i < 4; ++i) {
    int idx = tid + 512*i;
    int ch = idx & 31, px = idx >> 5;
    int pxg = (R0 + (px >> 3))*64 + C0 + (px & 7);
    size_t pix = (size_t)b*4096 + pxg;
    float ig = sm.ep.gates[ch*65 + px]        + a.bx[ch];
    float fg = sm.ep.gates[(ch+32)*65 + px]   + a.bx[ch+32];
    float gg = sm.ep.gates[(ch+64)*65 + px]   + a.bx[ch+64];
    float og = sm.ep.gates[(ch+96)*65 + px]   + a.bx[ch+96];
    float c  = a.cx_src[pix*32 + ch];
    float cn = sigm(fg + 0.01f)*c + sigm(ig)*tanhf(gg);
    float h  = sigm(og)*tanhf(cn);
    if (a.cx_dst) a.cx_dst[pix*32 + ch] = cn;
    unsigned short hh = bf16rn(h);
    unsigned short hl = bf16rn(h - bf2f(hh));
    if (a.hx_dst0) { a.hx_dst0[pix*192 + 32 + ch] = hh; a.hx_dst0[pix*192 + 128 + ch] = hl; }
    if (a.hx_dst1) { a.hx_dst1[pix*192 + 32 + ch] = hh; a.hx_dst1[pix*192 + 128 + ch] = hl; }
    sm.ep.hbuf[px*64 + ch] = h;
  }
  __syncthreads();

  // ---- phase 4: branch-Z gates -> LDS -> gating ----
#pragma unroll
  for (int t = 0; t < 4; ++t)
#pragma unroll
    for (int r = 0; r < 4; ++r) {
      int m = q*4 + r;
      int px = (2*t + (m >> 3))*8 + (m & 7);
      sm.ep.gates[co*65 + px] = accz[t][r];
    }
  __syncthreads();
#pragma unroll
  for (int i = 0; i < 4; ++i) {
    int idx = tid + 512*i;
    int ch = idx & 31, px = idx >> 5;
    int pxg = (R0 + (px >> 3))*64 + C0 + (px & 7);
    size_t pix = (size_t)b*4096 + pxg;
    float ig = sm.ep.gates[ch*65 + px]        + a.bz[ch];
    float fg = sm.ep.gates[(ch+32)*65 + px]   + a.bz[ch+32];
    float gg = sm.ep.gates[(ch+64)*65 + px]   + a.bz[ch+64];
    float og = sm.ep.gates[(ch+96)*65 + px]   + a.bz[ch+96];
    float c  = a.cz[pix*32 + ch];
    float cn = sigm(fg + 0.01f)*c + sigm(ig)*tanhf(gg);
    float h  = sigm(og)*tanhf(cn);
    a.cz[pix*32 + ch] = cn;
    unsigned short hh = bf16rn(h);
    unsigned short hl = bf16rn(h - bf2f(hh));
    if (a.hz_dst) { a.hz_dst[pix*192 + 64 + ch] = hh; a.hz_dst[pix*192 + 160 + ch] = hl; }
    sm.ep.hbuf[px*64 + 32 + ch] = h;
  }
  __syncthreads();

  // ---- phase 5: fused 1x1 y-conv (64 -> 32) ----
  if (a.wy) {
#pragma unroll 1
    for (int i = 0; i < 4; ++i) {
      int idx = tid + 512*i;
      int co2 = idx & 31, px = idx >> 5;
      int pxg = (R0 + (px >> 3))*64 + C0 + (px & 7);
      size_t pix = (size_t)b*4096 + pxg;
      float acc = a.by[co2];
#pragma unroll
      for (int c2 = 0; c2 < 64; ++c2) acc += a.wy[co2*64 + c2] * sm.ep.hbuf[px*64 + c2];
      if (a.y_dst) {
        unsigned short yh = bf16rn(acc);
        unsigned short yl = bf16rn(acc - bf2f(yh));
        a.y_dst[pix*192 + co2] = yh; a.y_dst[pix*192 + 96 + co2] = yl;
      }
      if (a.wl) sm.ep.ybuf[px*33 + co2] = acc;
    }
  }
  // ---- phase 6: fused pred-conv (32 -> 1), only cell (2,2) ----
  if (a.wl) {
    __syncthreads();
    if (tid < 64) {
      int px = tid;
      int pxg = (R0 + (px >> 3))*64 + C0 + (px & 7);
      float p = 0.f;
#pragma unroll
      for (int c2 = 0; c2 < 32; ++c2) p += a.wl[c2] * sm.ep.ybuf[px*33 + c2];
      a.pred_out[(size_t)b*4096 + pxg] = p;
      if (a.final_out) a.final_out[(size_t)b*40960 + pxg] = p;
    }
  }
}

extern "C" void kernel_launch(void* const* d_in, const int* in_sizes, int n_in,
                              void* d_out, int out_size, void* d_ws, size_t ws_size,
                              hipStream_t stream)
{
  const float* input_seq = (const float*)d_in[0];
  const float* w_x0 = (const float*)d_in[1];
  const float* b_x0 = (const float*)d_in[2];
  const float* w_z0 = (const float*)d_in[3];
  const float* b_z0 = (const float*)d_in[4];
  const float* w_y0 = (const float*)d_in[5];
  const float* b_y0 = (const float*)d_in[6];
  const float* w_x1 = (const float*)d_in[7];
  const float* b_x1 = (const float*)d_in[8];
  const float* w_z1 = (const float*)d_in[9];
  const float* b_z1 = (const float*)d_in[10];
  const float* w_y1 = (const float*)d_in[11];
  const float* b_y1 = (const float*)d_in[12];
  const float* w_last = (const float*)d_in[13];
  (void)in_sizes; (void)n_in; (void)out_size; (void)ws_size;

  uint8_t* wsb = (uint8_t*)d_ws;
  size_t off = 0;
  auto alloc = [&](size_t bytes) -> void* {
    void* p = wsb + off; off += (bytes + 255) & ~(size_t)255; return p;
  };

  const size_t CATB = (size_t)NB*HW*192*2;       // 6,291,456 B
  unsigned short* cat[3][3][2];
  for (int l = 0; l < 3; ++l)
    for (int s = 0; s < 3; ++s) {
      cat[l][s][0] = (unsigned short*)alloc(CATB);
      cat[l][s][1] = (s == 0) ? (unsigned short*)alloc(CATB) : cat[l][s][0];
    }
  const size_t CB = (size_t)NB*HW*32*4;          // 2,097,152 B
  float* cx[3][2]; float* cz[3];
  for (int l = 0; l < 3; ++l) { cx[l][0] = (float*)alloc(CB); cx[l][1] = (float*)alloc(CB); }
  for (int l = 0; l < 3; ++l) cz[l] = (float*)alloc(CB);
  size_t zero_bytes = off;                       // cats + cx + cz

  unsigned short *wxh[9], *wxl[9], *wzh[9], *wzl[9];
  for (int c = 0; c < 9; ++c) {
    wxh[c] = (unsigned short*)alloc(9*3*128*32*2);
    wxl[c] = (unsigned short*)alloc(9*3*128*32*2);
    wzh[c] = (unsigned short*)alloc(25*3*128*32*2);
    wzl[c] = (unsigned short*)alloc(25*3*128*32*2);
  }
  float* predbuf = (float*)alloc((size_t)18*NB*HW*4);

  // init: zero states + cat buffers (ws is poison-filled each call)
  zero4<<<2048, 256, 0, stream>>>((uint4*)wsb, zero_bytes/16);

  // pack weights (bf16 hi/lo, MFMA B-layout, cat-channel remap to uniform 96)
  for (int l = 0; l < 3; ++l)
    for (int s = 0; s < 3; ++s) {
      int cell = l*3 + s;
      const float *srcx, *srcz; int cin;
      if (l == 0) { srcx = w_x0 + (size_t)s*128*65*9;  srcz = w_z0 + (size_t)s*128*65*25;  cin = 65; }
      else { int li = (l-1)*3 + s;
             srcx = w_x1 + (size_t)li*128*96*9; srcz = w_z1 + (size_t)li*128*96*25; cin = 96; }
      pack_w<<<(9*3*128*32)/256, 256, 0, stream>>>(srcx, wxh[cell], wxl[cell], 9, cin, l==0);
      pack_w<<<(25*3*128*32)/256, 256, 0, stream>>>(srcz, wzh[cell], wzl[cell], 25, cin, l==0);
    }

  for (int step = 0; step < 18; ++step) {
    int par = step & 1, npar = par ^ 1;
    frame_fill<<<dim3(64,3), 256, 0, stream>>>(input_seq, predbuf, step,
        cat[0][0][par], cat[0][1][0], cat[0][2][0]);
    for (int l = 0; l < 3; ++l)
      for (int s = 0; s < 3; ++s) {
        int cell = l*3 + s;
        CellArgs A;
        A.cat_in = cat[l][s][(s==0) ? par : 0];
        A.wxh = wxh[cell]; A.wxl = wxl[cell]; A.wzh = wzh[cell]; A.wzl = wzl[cell];
        if (l == 0) { A.bx = b_x0 + s*128; A.bz = b_z0 + s*128; }
        else { int li = (l-1)*3 + s; A.bx = b_x1 + li*128; A.bz = b_z1 + li*128; }
        A.cx_src = (s == 2) ? cx[l][1] : cx[l][0];
        A.cx_dst = (s == 0) ? cx[l][0] : ((s == 1) ? cx[l][1] : nullptr);
        A.cz = cz[l];
        A.hx_dst0 = (s == 0) ? cat[l][1][0] : ((s == 1) ? cat[l][2][0] : nullptr);
        A.hx_dst1 = (s == 0) ? cat[l][0][npar] : nullptr;
        A.hz_dst  = (s < 2) ? cat[l][s+1][0] : cat[l][0][npar];
        A.wy = nullptr; A.by = nullptr; A.y_dst = nullptr;
        A.wl = nullptr; A.pred_out = nullptr; A.final_out = nullptr;
        if (l < 2) {
          if (l == 0) { A.wy = w_y0 + (size_t)s*32*64; A.by = b_y0 + s*32; }
          else        { A.wy = w_y1 + (size_t)s*32*64; A.by = b_y1 + s*32; }
          A.y_dst = cat[l+1][s][(s==0) ? par : 0];
        } else if (s == 2) {
          A.wy = w_y1 + (size_t)5*32*64; A.by = b_y1 + 5*32;
          A.wl = w_last;
          A.pred_out = predbuf + (size_t)step*NB*HW;
          A.final_out = (step >= 8) ? ((float*)d_out + (size_t)(step-8)*HW) : nullptr;
        }
        cell_kernel<<<dim3(64, NB), 512, 0, stream>>>(A);
      }
  }
}

// Round 3
// 7559.176 us; speedup vs baseline: 11.9212x; 1.7594x over previous
//
#include <hip/hip_runtime.h>
#include <cstddef>
#include <cstdint>

// CubicRNN MI355X — round 3: conflict-free chunk-major LDS, Ng=4 x Kg=2 wave
// tiling (each wave: 64 px x 32 co, half the K-units), cross-wave K-reduction.
// Split-bf16 (hi,lo) arithmetic identical to round 2 (absmax 1.86e-9 verified).

typedef __attribute__((ext_vector_type(8))) short bf16x8;
typedef __attribute__((ext_vector_type(4))) float f32x4;

#define HW 4096
#define NB 4

__device__ __forceinline__ float sigm(float x){ return 1.f/(1.f+expf(-x)); }
__device__ __forceinline__ unsigned short bf16rn(float x){
  unsigned int u = __float_as_uint(x);
  u = (u + 0x7FFFu + ((u>>16)&1u)) >> 16;
  return (unsigned short)u;
}
__device__ __forceinline__ float bf2f(unsigned short h){ return __uint_as_float(((unsigned int)h)<<16); }

__global__ __launch_bounds__(256) void zero4(uint4* __restrict__ p, size_t n){
  size_t i = (size_t)blockIdx.x*blockDim.x + threadIdx.x;
  size_t st = (size_t)gridDim.x*blockDim.x;
  uint4 z = make_uint4(0u,0u,0u,0u);
  for (; i < n; i += st) p[i] = z;
}

// Pack conv weights (fp32 OIHW) -> [unit=tap*3+kc][co(128)][k(32)] bf16 hi/lo,
// cat channels remapped to uniform 96 (layer0: ci0->k0, ci1..64->k32..95).
__global__ __launch_bounds__(256) void pack_w(const float* __restrict__ src,
    unsigned short* __restrict__ dh, unsigned short* __restrict__ dl,
    int taps, int cin, int l0){
  int idx = blockIdx.x*256 + threadIdx.x;
  int k = idx & 31, co = (idx>>5) & 127, rest = idx >> 12;
  int tap = rest/3, kc = rest - tap*3;
  int p = kc*32 + k;
  int ci = l0 ? ((p==0) ? 0 : ((p>=32) ? p-31 : -1)) : p;
  float wv = 0.f;
  if (ci >= 0 && ci < cin) wv = src[((size_t)co*cin + ci)*taps + tap];
  unsigned short h = bf16rn(wv);
  unsigned short l = bf16rn(wv - bf2f(h));
  dh[idx] = h; dl[idx] = l;
}

// Write frame (or fed-back pred) into ch0 (hi) / ch96 (lo) of layer-0 cat bufs.
__global__ __launch_bounds__(256) void frame_fill(const float* __restrict__ inseq,
    const float* __restrict__ predbuf, int step,
    unsigned short* __restrict__ c0, unsigned short* __restrict__ c1,
    unsigned short* __restrict__ c2){
  int s = blockIdx.y;
  unsigned short* dst = (s==0) ? c0 : ((s==1) ? c1 : c2);
  int i = blockIdx.x*256 + threadIdx.x;          // b*4096 + px
  int b = i >> 12, px = i & 4095;
  int j = step + s;
  float v = (j < 10) ? inseq[((size_t)b*10 + j)*HW + px]
                     : predbuf[(size_t)(j-3)*(NB*HW) + (size_t)b*HW + px];
  unsigned short h = bf16rn(v);
  unsigned short l = bf16rn(v - bf2f(h));
  size_t base = (size_t)i * 192;
  dst[base] = h; dst[base + 96] = l;
}

struct CellArgs {
  const unsigned short* cat_in;                  // [B][4096][192] bf16 hi[96],lo[96]
  const unsigned short *wxh, *wxl, *wzh, *wzl;   // packed weights
  const float *bx, *bz;                          // [128]
  const float *cx_src; float *cx_dst;            // [B][4096][32] fp32
  float *cz;                                     // in-place
  unsigned short *hx_dst0, *hx_dst1, *hz_dst;    // cat bases (null = skip)
  const float *wy, *by;                          // [32][64],[32]
  unsigned short *y_dst;                         // cat base ch0 (null = skip)
  const float *wl;                               // [32]; non-null = pred mode
  float *pred_out;
  float *final_out;                              // d_out + ti*4096 (b-stride 40960)
};

// LDS layout (bytes):
//   [0, 55680)      A-halo: uint4 index (half*12 + chunk)*145 + px
//                   (half=hi/lo, chunk=ci-octet kc*4+q in [0,12), px in [0,144))
//   overlay after K-loop: pbuf f32 [0,16384), gates f32 at 16384 (32px x 132)
//   [55680, 73088)  hbuf f32 [64px][68]
//   [73088, 82560)  ybuf f32 [64px][37]
#define LDS_BYTES 82560

__global__ __launch_bounds__(512, 2) void cell_kernel(CellArgs a){
  __shared__ __align__(16) char smem[LDS_BYTES];
  uint4*  AU4    = (uint4*)smem;
  float*  pbufF  = (float*)smem;
  float*  gatesF = (float*)(smem + 16384);
  float*  hbufF  = (float*)(smem + 55680);
  float*  ybufF  = (float*)(smem + 73088);

  const int tid = threadIdx.x;
  const int b = blockIdx.y;
  const int reg = blockIdx.x;
  const int R0 = (reg >> 3) << 3, C0 = (reg & 7) << 3;   // 8x8 pixel region

  // ---- phase 0: stage 12x12 halo, 96ch hi+lo, chunk-major ----
  for (int i = tid; i < 3456; i += 512) {
    int px = i % 144, cp = i / 144;              // px-major: LDS banks spread
    int hr = px / 12, hc = px - hr*12;
    int gy = R0 + hr - 2, gx = C0 + hc - 2;
    uint4 v = make_uint4(0u,0u,0u,0u);
    if (gy >= 0 && gy < 64 && gx >= 0 && gx < 64) {
      size_t pix = (size_t)b*4096 + gy*64 + gx;
      v = *reinterpret_cast<const uint4*>(a.cat_in + pix*192 + cp*8);
    }
    AU4[cp*145 + px] = v;                        // cp = half*12+chunk directly
  }
  __syncthreads();

  // ---- phase 1: K-loop (barrier-free) ----
  const int wave = tid >> 6, lane = tid & 63;
  const int n = wave & 3, kg = wave >> 2;        // Ng=4 co-groups, Kg=2 K-groups
  const int q = lane >> 4, n16 = lane & 15;
  const int row_in = n16 >> 3, col = n16 & 7;
  const int kq = q*8;
  const int co0 = n*32 + n16;                    // Nfrag0; Nfrag1 = co0+16

  f32x4 zf = {0.f,0.f,0.f,0.f};
  f32x4 accz[2][4], accx[2][4];
#pragma unroll
  for (int nf = 0; nf < 2; ++nf)
#pragma unroll
    for (int m = 0; m < 4; ++m) { accz[nf][m] = zf; accx[nf][m] = zf; }

#pragma unroll 1
  for (int u = kg; u < 75; u += 2) {
    int tap = u/3, kc = u - tap*3;
    int ky = tap/5, kx = tap - ky*5;
    bool inner = ((unsigned)(ky-1) <= 2u) && ((unsigned)(kx-1) <= 2u);

    // B fragments (global, coalesced 1KB per load)
    const unsigned short* zb = a.wzh + (size_t)u*4096 + co0*32 + kq;
    const unsigned short* zlb = a.wzl + (size_t)u*4096 + co0*32 + kq;
    bf16x8 Bzh[2], Bzl[2];
    Bzh[0] = *(const bf16x8*)zb;   Bzh[1] = *(const bf16x8*)(zb + 512);
    Bzl[0] = *(const bf16x8*)zlb;  Bzl[1] = *(const bf16x8*)(zlb + 512);
    bf16x8 Bxh[2], Bxl[2];
    if (inner) {
      int xu = ((ky-1)*3 + (kx-1))*3 + kc;
      const unsigned short* xb = a.wxh + (size_t)xu*4096 + co0*32 + kq;
      const unsigned short* xlb = a.wxl + (size_t)xu*4096 + co0*32 + kq;
      Bxh[0] = *(const bf16x8*)xb;   Bxh[1] = *(const bf16x8*)(xb + 512);
      Bxl[0] = *(const bf16x8*)xlb;  Bxl[1] = *(const bf16x8*)(xlb + 512);
    }

    // A fragments from LDS (conflict-free chunk-major)
    int cbase = (kc*4 + q)*145;
    int pxb = (row_in + ky)*12 + col + kx;
    bf16x8 Ah[4], Al[4];
#pragma unroll
    for (int m = 0; m < 4; ++m) {
      int ai = cbase + pxb + m*24;
      Ah[m] = *(const bf16x8*)(AU4 + ai);
      Al[m] = *(const bf16x8*)(AU4 + 1740 + ai);   // +12*145
    }

#pragma unroll
    for (int nf = 0; nf < 2; ++nf)
#pragma unroll
      for (int m = 0; m < 4; ++m) {
        accz[nf][m] = __builtin_amdgcn_mfma_f32_16x16x32_bf16(Ah[m], Bzh[nf], accz[nf][m], 0,0,0);
        accz[nf][m] = __builtin_amdgcn_mfma_f32_16x16x32_bf16(Al[m], Bzh[nf], accz[nf][m], 0,0,0);
        accz[nf][m] = __builtin_amdgcn_mfma_f32_16x16x32_bf16(Ah[m], Bzl[nf], accz[nf][m], 0,0,0);
      }
    if (inner) {
#pragma unroll
      for (int nf = 0; nf < 2; ++nf)
#pragma unroll
        for (int m = 0; m < 4; ++m) {
          accx[nf][m] = __builtin_amdgcn_mfma_f32_16x16x32_bf16(Ah[m], Bxh[nf], accx[nf][m], 0,0,0);
          accx[nf][m] = __builtin_amdgcn_mfma_f32_16x16x32_bf16(Al[m], Bxh[nf], accx[nf][m], 0,0,0);
          accx[nf][m] = __builtin_amdgcn_mfma_f32_16x16x32_bf16(Ah[m], Bxl[nf], accx[nf][m], 0,0,0);
        }
    }
  }
  __syncthreads();

  // ---- phase 2: K-reduce + gating, conv-at-a-time, half-M passes ----
  for (int cv = 0; cv < 2; ++cv) {               // 0 = z-branch, 1 = x-branch
    for (int hf = 0; hf < 2; ++hf) {             // Mfrags {0,1} then {2,3}
      if (kg == 1) {
#pragma unroll
        for (int ml = 0; ml < 2; ++ml) {
          int m = hf*2 + ml;
#pragma unroll
          for (int nf = 0; nf < 2; ++nf)
#pragma unroll
            for (int r = 0; r < 4; ++r)
              pbufF[(((n*2 + ml)*2 + nf)*4 + r)*64 + lane] =
                  cv ? accx[nf][m][r] : accz[nf][m][r];
        }
      }
      __syncthreads();
      if (kg == 0) {
#pragma unroll
        for (int ml = 0; ml < 2; ++ml) {
          int m = hf*2 + ml;
#pragma unroll
          for (int nf = 0; nf < 2; ++nf)
#pragma unroll
            for (int r = 0; r < 4; ++r) {
              float s = (cv ? accx[nf][m][r] : accz[nf][m][r])
                      + pbufF[(((n*2 + ml)*2 + nf)*4 + r)*64 + lane];
              int p16 = q*4 + r;
              int lpx = (2*ml + (p16 >> 3))*8 + (p16 & 7);   // 0..31 in this half
              gatesF[lpx*132 + n*32 + nf*16 + n16] = s;
            }
        }
      }
      __syncthreads();
      // gating for these 32 px
      const float* bias = cv ? a.bx : a.bz;
#pragma unroll
      for (int it = 0; it < 2; ++it) {
        int idx = tid + it*512;
        int ch = idx & 31, lpx = idx >> 5;
        int px = hf*32 + lpx;
        int pxg = (R0 + (px >> 3))*64 + C0 + (px & 7);
        size_t pix = (size_t)b*4096 + pxg;
        float ig = gatesF[lpx*132 + ch]      + bias[ch];
        float fg = gatesF[lpx*132 + ch + 32] + bias[ch + 32];
        float gg = gatesF[lpx*132 + ch + 64] + bias[ch + 64];
        float og = gatesF[lpx*132 + ch + 96] + bias[ch + 96];
        if (cv == 0) {
          float c = a.cz[pix*32 + ch];
          float cn = sigm(fg + 0.01f)*c + sigm(ig)*tanhf(gg);
          float h = sigm(og)*tanhf(cn);
          a.cz[pix*32 + ch] = cn;
          unsigned short hh = bf16rn(h), hl = bf16rn(h - bf2f(hh));
          if (a.hz_dst) { a.hz_dst[pix*192 + 64 + ch] = hh; a.hz_dst[pix*192 + 160 + ch] = hl; }
          hbufF[px*68 + 32 + ch] = h;
        } else {
          float c = a.cx_src[pix*32 + ch];
          float cn = sigm(fg + 0.01f)*c + sigm(ig)*tanhf(gg);
          float h = sigm(og)*tanhf(cn);
          if (a.cx_dst) a.cx_dst[pix*32 + ch] = cn;
          unsigned short hh = bf16rn(h), hl = bf16rn(h - bf2f(hh));
          if (a.hx_dst0) { a.hx_dst0[pix*192 + 32 + ch] = hh; a.hx_dst0[pix*192 + 128 + ch] = hl; }
          if (a.hx_dst1) { a.hx_dst1[pix*192 + 32 + ch] = hh; a.hx_dst1[pix*192 + 128 + ch] = hl; }
          hbufF[px*68 + ch] = h;
        }
      }
      __syncthreads();
    }
  }

  // ---- phase 3: fused 1x1 y-conv (64 -> 32) ----
  if (a.wy) {
#pragma unroll 1
    for (int it = 0; it < 4; ++it) {
      int idx = tid + it*512;
      int co2 = idx & 31, px = idx >> 5;
      int pxg = (R0 + (px >> 3))*64 + C0 + (px & 7);
      size_t pix = (size_t)b*4096 + pxg;
      float acc = a.by[co2];
#pragma unroll
      for (int c2 = 0; c2 < 64; ++c2) acc += a.wy[co2*64 + c2] * hbufF[px*68 + c2];
      if (a.y_dst) {
        unsigned short yh = bf16rn(acc), yl = bf16rn(acc - bf2f(yh));
        a.y_dst[pix*192 + co2] = yh; a.y_dst[pix*192 + 96 + co2] = yl;
      }
      if (a.wl) ybufF[px*37 + co2] = acc;
    }
  }
  // ---- phase 4: fused pred-conv (32 -> 1), last cell only ----
  if (a.wl) {
    __syncthreads();
    if (tid < 64) {
      int px = tid;
      int pxg = (R0 + (px >> 3))*64 + C0 + (px & 7);
      float p = 0.f;
#pragma unroll
      for (int c2 = 0; c2 < 32; ++c2) p += a.wl[c2] * ybufF[px*37 + c2];
      a.pred_out[(size_t)b*4096 + pxg] = p;
      if (a.final_out) a.final_out[(size_t)b*40960 + pxg] = p;
    }
  }
}

extern "C" void kernel_launch(void* const* d_in, const int* in_sizes, int n_in,
                              void* d_out, int out_size, void* d_ws, size_t ws_size,
                              hipStream_t stream)
{
  const float* input_seq = (const float*)d_in[0];
  const float* w_x0 = (const float*)d_in[1];
  const float* b_x0 = (const float*)d_in[2];
  const float* w_z0 = (const float*)d_in[3];
  const float* b_z0 = (const float*)d_in[4];
  const float* w_y0 = (const float*)d_in[5];
  const float* b_y0 = (const float*)d_in[6];
  const float* w_x1 = (const float*)d_in[7];
  const float* b_x1 = (const float*)d_in[8];
  const float* w_z1 = (const float*)d_in[9];
  const float* b_z1 = (const float*)d_in[10];
  const float* w_y1 = (const float*)d_in[11];
  const float* b_y1 = (const float*)d_in[12];
  const float* w_last = (const float*)d_in[13];
  (void)in_sizes; (void)n_in; (void)out_size; (void)ws_size;

  uint8_t* wsb = (uint8_t*)d_ws;
  size_t off = 0;
  auto alloc = [&](size_t bytes) -> void* {
    void* p = wsb + off; off += (bytes + 255) & ~(size_t)255; return p;
  };

  const size_t CATB = (size_t)NB*HW*192*2;       // 6,291,456 B
  unsigned short* cat[3][3][2];
  for (int l = 0; l < 3; ++l)
    for (int s = 0; s < 3; ++s) {
      cat[l][s][0] = (unsigned short*)alloc(CATB);
      cat[l][s][1] = (s == 0) ? (unsigned short*)alloc(CATB) : cat[l][s][0];
    }
  const size_t CB = (size_t)NB*HW*32*4;          // 2,097,152 B
  float* cx[3][2]; float* cz[3];
  for (int l = 0; l < 3; ++l) { cx[l][0] = (float*)alloc(CB); cx[l][1] = (float*)alloc(CB); }
  for (int l = 0; l < 3; ++l) cz[l] = (float*)alloc(CB);
  size_t zero_bytes = off;                       // cats + cx + cz

  unsigned short *wxh[9], *wxl[9], *wzh[9], *wzl[9];
  for (int c = 0; c < 9; ++c) {
    wxh[c] = (unsigned short*)alloc(9*3*128*32*2);
    wxl[c] = (unsigned short*)alloc(9*3*128*32*2);
    wzh[c] = (unsigned short*)alloc(25*3*128*32*2);
    wzl[c] = (unsigned short*)alloc(25*3*128*32*2);
  }
  float* predbuf = (float*)alloc((size_t)18*NB*HW*4);

  zero4<<<2048, 256, 0, stream>>>((uint4*)wsb, zero_bytes/16);

  for (int l = 0; l < 3; ++l)
    for (int s = 0; s < 3; ++s) {
      int cell = l*3 + s;
      const float *srcx, *srcz; int cin;
      if (l == 0) { srcx = w_x0 + (size_t)s*128*65*9;  srcz = w_z0 + (size_t)s*128*65*25;  cin = 65; }
      else { int li = (l-1)*3 + s;
             srcx = w_x1 + (size_t)li*128*96*9; srcz = w_z1 + (size_t)li*128*96*25; cin = 96; }
      pack_w<<<(9*3*128*32)/256, 256, 0, stream>>>(srcx, wxh[cell], wxl[cell], 9, cin, l==0);
      pack_w<<<(25*3*128*32)/256, 256, 0, stream>>>(srcz, wzh[cell], wzl[cell], 25, cin, l==0);
    }

  for (int step = 0; step < 18; ++step) {
    int par = step & 1, npar = par ^ 1;
    frame_fill<<<dim3(64,3), 256, 0, stream>>>(input_seq, predbuf, step,
        cat[0][0][par], cat[0][1][0], cat[0][2][0]);
    for (int l = 0; l < 3; ++l)
      for (int s = 0; s < 3; ++s) {
        int cell = l*3 + s;
        CellArgs A;
        A.cat_in = cat[l][s][(s==0) ? par : 0];
        A.wxh = wxh[cell]; A.wxl = wxl[cell]; A.wzh = wzh[cell]; A.wzl = wzl[cell];
        if (l == 0) { A.bx = b_x0 + s*128; A.bz = b_z0 + s*128; }
        else { int li = (l-1)*3 + s; A.bx = b_x1 + li*128; A.bz = b_z1 + li*128; }
        A.cx_src = (s == 2) ? cx[l][1] : cx[l][0];
        A.cx_dst = (s == 0) ? cx[l][0] : ((s == 1) ? cx[l][1] : nullptr);
        A.cz = cz[l];
        A.hx_dst0 = (s == 0) ? cat[l][1][0] : ((s == 1) ? cat[l][2][0] : nullptr);
        A.hx_dst1 = (s == 0) ? cat[l][0][npar] : nullptr;
        A.hz_dst  = (s < 2) ? cat[l][s+1][0] : cat[l][0][npar];
        A.wy = nullptr; A.by = nullptr; A.y_dst = nullptr;
        A.wl = nullptr; A.pred_out = nullptr; A.final_out = nullptr;
        if (l < 2) {
          if (l == 0) { A.wy = w_y0 + (size_t)s*32*64; A.by = b_y0 + s*32; }
          else        { A.wy = w_y1 + (size_t)s*32*64; A.by = b_y1 + s*32; }
          A.y_dst = cat[l+1][s][(s==0) ? par : 0];
        } else if (s == 2) {
          A.wy = w_y1 + (size_t)5*32*64; A.by = b_y1 + 5*32;
          A.wl = w_last;
          A.pred_out = predbuf + (size_t)step*NB*HW;
          A.final_out = (step >= 8) ? ((float*)d_out + (size_t)(step-8)*HW) : nullptr;
        }
        cell_kernel<<<dim3(64, NB), 512, 0, stream>>>(A);
      }
  }
}

// Round 4
// 6079.580 us; speedup vs baseline: 14.8225x; 1.2434x over previous
//
#include <hip/hip_runtime.h>
#include <cstddef>
#include <cstdint>

// CubicRNN MI355X — round 4: split-f16 activations (hi,lo) x single-f16 weights
// (2 MFMAs per logical product), Ng=2 x Kg=4 wave tiling, depth-1 B-prefetch,
// chunk-planar cat layout for coalesced halo staging.
// B=4, T=10, C=1, H=W=64, HC=32, S=3, L=3, kx=3, kz=5, ky=1, 18 steps.

typedef __attribute__((ext_vector_type(8))) _Float16 f16x8;
typedef __attribute__((ext_vector_type(4))) float f32x4;
typedef unsigned short u16;

#define HW 4096
#define NB 4

__device__ __forceinline__ float sigm(float x){ return 1.f/(1.f+expf(-x)); }
__device__ __forceinline__ u16 f2h(float x){
  _Float16 h = (_Float16)x;
  union { _Float16 f; u16 u; } c; c.f = h; return c.u;
}

__global__ __launch_bounds__(256) void zero4(uint4* __restrict__ p, size_t n){
  size_t i = (size_t)blockIdx.x*blockDim.x + threadIdx.x;
  size_t st = (size_t)gridDim.x*blockDim.x;
  uint4 z = make_uint4(0u,0u,0u,0u);
  for (; i < n; i += st) p[i] = z;
}

// Pack conv weights (fp32 OIHW) -> [unit=tap*3+kc][co(128)][k(32)] f16 single,
// cat channels remapped to uniform 96 (layer0: ci0->k0, ci1..64->k32..95).
__global__ __launch_bounds__(256) void pack_w(const float* __restrict__ src,
    u16* __restrict__ dst, int taps, int cin, int l0){
  int idx = blockIdx.x*256 + threadIdx.x;
  int k = idx & 31, co = (idx>>5) & 127, rest = idx >> 12;
  int tap = rest/3, kc = rest - tap*3;
  int p = kc*32 + k;
  int ci = l0 ? ((p==0) ? 0 : ((p>=32) ? p-31 : -1)) : p;
  float wv = 0.f;
  if (ci >= 0 && ci < cin) wv = src[((size_t)co*cin + ci)*taps + tap];
  dst[idx] = f2h(wv);
}

// cat layout: [b][chunk 0..23][pixel 0..4095][elem 0..7] f16
// chunk = half*12 + (logical_slot>>3); half 0 = hi, 1 = lo; elem = slot&7.
__device__ __forceinline__ void put_pair(u16* base, int b, int slot, int pix, float v){
  _Float16 h = (_Float16)v;
  float lof = v - (float)h;
  size_t o = ((size_t)(b*24 + (slot>>3))*4096 + pix)*8 + (slot&7);
  base[o] = f2h(v);
  base[o + (size_t)393216] = f2h(lof);   // +12 chunks
}

// Write frame (or fed-back pred) into slot 0 of layer-0 cat bufs.
__global__ __launch_bounds__(256) void frame_fill(const float* __restrict__ inseq,
    const float* __restrict__ predbuf, int step,
    u16* __restrict__ c0, u16* __restrict__ c1, u16* __restrict__ c2){
  int s = blockIdx.y;
  u16* dst = (s==0) ? c0 : ((s==1) ? c1 : c2);
  int i = blockIdx.x*256 + threadIdx.x;          // b*4096 + px
  int b = i >> 12, px = i & 4095;
  int j = step + s;
  float v = (j < 10) ? inseq[((size_t)b*10 + j)*HW + px]
                     : predbuf[(size_t)(j-3)*(NB*HW) + (size_t)b*HW + px];
  put_pair(dst, b, 0, px, v);
}

struct CellArgs {
  const u16* cat_in;                       // chunk-planar f16 pairs
  const u16* wz; const u16* wx;            // packed f16 weights
  const float *bx, *bz;                    // [128]
  const float* cx_src; float* cx_dst;      // [B][4096][32] fp32 (dst may be null)
  float* cz;                               // in-place
  u16 *hx0, *hx1, *hz, *y_dst;             // cat base pointers (null = skip)
  const float *wy, *by;                    // [32][64],[32]
  const float *wl;                         // [32]; non-null = pred mode
  float *pred_out;                         // predbuf slot [B][4096]
  float *final_out;                        // d_out + ti*4096 (b-stride 40960) or null
};

// LDS: [0,55680) halo (24 chunks x 145 uint4); overlay after K-loop:
//   exch f32x4 [0,65536) ; hbuf f32 [65536, 82944) [64px][68] ;
//   ybuf f32 [82944, 92416) [64px][37]
#define LDS_BYTES 92416

__global__ __launch_bounds__(512, 2) void cell_kernel(CellArgs a){
  __shared__ __align__(16) char smem[LDS_BYTES];
  uint4* AU4   = (uint4*)smem;
  f32x4* exch  = (f32x4*)smem;             // 4096 entries = 64 KB
  float* hbufF = (float*)(smem + 65536);
  float* ybufF = (float*)(smem + 82944);

  const int tid = threadIdx.x;
  const int b = blockIdx.y;
  const int reg = blockIdx.x;
  const int R0 = (reg >> 3) << 3, C0 = (reg & 7) << 3;   // 8x8 pixel region

  // ---- phase 0: stage 12x12 halo, 24 chunk-planes, coalesced ----
  for (int i = tid; i < 3456; i += 512) {
    int px = i % 144, cp = i / 144;
    int hr = px / 12, hc = px - hr*12;
    int gy = R0 + hr - 2, gx = C0 + hc - 2;
    uint4 v = make_uint4(0u,0u,0u,0u);
    if (gy >= 0 && gy < 64 && gx >= 0 && gx < 64)
      v = *reinterpret_cast<const uint4*>(a.cat_in + ((size_t)(b*24 + cp)*4096 + gy*64 + gx)*8);
    AU4[cp*145 + px] = v;
  }
  __syncthreads();

  // ---- phase 1: K-loop, Ng=2 (64 co/wave) x Kg=4 ----
  const int wave = tid >> 6, lane = tid & 63;
  const int n = wave & 1, kg = wave >> 1;
  const int q = lane >> 4, n16 = lane & 15;
  const int row_in = n16 >> 3, col = n16 & 7;
  const int cb = n*64;
  const int wlo = (cb + n16)*32 + q*8;     // lane weight offset (nf adds 512)

  f32x4 zf = {0.f,0.f,0.f,0.f};
  f32x4 accz[4][4], accx[4][4];            // [nf][m]
#pragma unroll
  for (int nf = 0; nf < 4; ++nf)
#pragma unroll
    for (int m = 0; m < 4; ++m) { accz[nf][m] = zf; accx[nf][m] = zf; }

  f16x8 Bz[4];
#pragma unroll
  for (int nf = 0; nf < 4; ++nf)
    Bz[nf] = *(const f16x8*)(a.wz + (size_t)kg*4096 + wlo + nf*512);

#pragma unroll 1
  for (int u = kg; u < 75; u += 4) {
    int tap = u/3, kc = u - tap*3;
    int ky = tap/5, kx = tap - ky*5;
    bool inner = ((unsigned)(ky-1) <= 2u) && ((unsigned)(kx-1) <= 2u);

    f16x8 Bx[4];
    if (inner) {
      int xu = ((ky-1)*3 + (kx-1))*3 + kc;
#pragma unroll
      for (int nf = 0; nf < 4; ++nf)
        Bx[nf] = *(const f16x8*)(a.wx + (size_t)xu*4096 + wlo + nf*512);
    }

    int ai0 = (kc*4 + q)*145 + (row_in + ky)*12 + col + kx;
    f16x8 Ah[4], Al[4];
#pragma unroll
    for (int m = 0; m < 4; ++m) {
      Ah[m] = *(const f16x8*)(AU4 + ai0 + m*24);
      Al[m] = *(const f16x8*)(AU4 + 1740 + ai0 + m*24);
    }

#pragma unroll
    for (int nf = 0; nf < 4; ++nf)
#pragma unroll
      for (int m = 0; m < 4; ++m)
        accz[nf][m] = __builtin_amdgcn_mfma_f32_16x16x32_f16(Ah[m], Bz[nf], accz[nf][m], 0,0,0);

    // prefetch next z-B (depth-1, hides L2 latency)
    int un = (u + 4 < 75) ? u + 4 : kg;
    f16x8 Bzn[4];
#pragma unroll
    for (int nf = 0; nf < 4; ++nf)
      Bzn[nf] = *(const f16x8*)(a.wz + (size_t)un*4096 + wlo + nf*512);

#pragma unroll
    for (int nf = 0; nf < 4; ++nf)
#pragma unroll
      for (int m = 0; m < 4; ++m)
        accz[nf][m] = __builtin_amdgcn_mfma_f32_16x16x32_f16(Al[m], Bz[nf], accz[nf][m], 0,0,0);

    if (inner) {
#pragma unroll
      for (int nf = 0; nf < 4; ++nf)
#pragma unroll
        for (int m = 0; m < 4; ++m) {
          accx[nf][m] = __builtin_amdgcn_mfma_f32_16x16x32_f16(Ah[m], Bx[nf], accx[nf][m], 0,0,0);
          accx[nf][m] = __builtin_amdgcn_mfma_f32_16x16x32_f16(Al[m], Bx[nf], accx[nf][m], 0,0,0);
        }
    }
#pragma unroll
    for (int nf = 0; nf < 4; ++nf) Bz[nf] = Bzn[nf];
  }

  // ---- phase 2: K-reduce (4-way) fused with gating, 4 passes ----
#pragma unroll
  for (int pass = 0; pass < 4; ++pass) {
    const int br = pass >> 1, mh = pass & 1;       // br0=z, br1=x; Mfrags {2mh,2mh+1}
    __syncthreads();                               // exch free (halo dead / prev pass read)
#pragma unroll
    for (int nf = 0; nf < 4; ++nf)
#pragma unroll
      for (int ml = 0; ml < 2; ++ml) {
        int m = mh*2 + ml;
        exch[((((kg*2 + n)*4 + nf)*2 + ml)*64) + lane] = br ? accx[nf][m] : accz[nf][m];
      }
    __syncthreads();
    if (tid < 256) {
      int ch = tid & 31, pxq = tid >> 5;           // 8 px-quads x 32 channels
      int ml = pxq >> 2, qq = pxq & 3;
      const float* bias = br ? a.bx : a.bz;
      float gsum[4][4];                            // [gate][r]
#pragma unroll
      for (int g = 0; g < 4; ++g) {
        int co = g*32 + ch;
        int nn = co >> 6, nf = (co >> 4) & 3, nl = co & 15;
        int li = qq*16 + nl;
        f32x4 s = zf;
#pragma unroll
        for (int kgg = 0; kgg < 4; ++kgg)
          s += exch[((((kgg*2 + nn)*4 + nf)*2 + ml)*64) + li];
        float bb = bias[co];
#pragma unroll
        for (int r = 0; r < 4; ++r) gsum[g][r] = s[r] + bb;
      }
#pragma unroll
      for (int r = 0; r < 4; ++r) {
        int p16 = qq*4 + r;
        int m = mh*2 + ml;
        int px = (2*m + (p16 >> 3))*8 + (p16 & 7);
        int pxg = (R0 + (px >> 3))*64 + C0 + (px & 7);
        size_t pix = (size_t)b*4096 + pxg;
        float ig = gsum[0][r], fg = gsum[1][r], gg = gsum[2][r], og = gsum[3][r];
        if (br == 0) {                             // z-branch
          float c = a.cz[pix*32 + ch];
          float cn = sigm(fg + 0.01f)*c + sigm(ig)*tanhf(gg);
          float h = sigm(og)*tanhf(cn);
          a.cz[pix*32 + ch] = cn;
          if (a.hz) put_pair(a.hz, b, 64 + ch, pxg, h);
          hbufF[px*68 + 32 + ch] = h;
        } else {                                   // x-branch
          float c = a.cx_src[pix*32 + ch];
          float cn = sigm(fg + 0.01f)*c + sigm(ig)*tanhf(gg);
          float h = sigm(og)*tanhf(cn);
          if (a.cx_dst) a.cx_dst[pix*32 + ch] = cn;
          if (a.hx0) put_pair(a.hx0, b, 32 + ch, pxg, h);
          if (a.hx1) put_pair(a.hx1, b, 32 + ch, pxg, h);
          hbufF[px*68 + ch] = h;
        }
      }
    }
  }
  __syncthreads();

  // ---- phase 3: fused 1x1 y-conv (64 -> 32) ----
  if (a.wy) {
#pragma unroll 1
    for (int it = 0; it < 4; ++it) {
      int idx = tid + it*512;
      int co2 = idx & 31, px = idx >> 5;
      int pxg = (R0 + (px >> 3))*64 + C0 + (px & 7);
      float acc = a.by[co2];
#pragma unroll
      for (int c2 = 0; c2 < 64; ++c2) acc += a.wy[co2*64 + c2] * hbufF[px*68 + c2];
      if (a.y_dst) put_pair(a.y_dst, b, co2, pxg, acc);
      if (a.wl) ybufF[px*37 + co2] = acc;
    }
  }
  // ---- phase 4: fused pred-conv (32 -> 1), last cell only ----
  if (a.wl) {
    __syncthreads();
    if (tid < 64) {
      int px = tid;
      int pxg = (R0 + (px >> 3))*64 + C0 + (px & 7);
      float p = 0.f;
#pragma unroll
      for (int c2 = 0; c2 < 32; ++c2) p += a.wl[c2] * ybufF[px*37 + c2];
      a.pred_out[(size_t)b*4096 + pxg] = p;
      if (a.final_out) a.final_out[(size_t)b*40960 + pxg] = p;
    }
  }
}

extern "C" void kernel_launch(void* const* d_in, const int* in_sizes, int n_in,
                              void* d_out, int out_size, void* d_ws, size_t ws_size,
                              hipStream_t stream)
{
  const float* input_seq = (const float*)d_in[0];
  const float* w_x0 = (const float*)d_in[1];
  const float* b_x0 = (const float*)d_in[2];
  const float* w_z0 = (const float*)d_in[3];
  const float* b_z0 = (const float*)d_in[4];
  const float* w_y0 = (const float*)d_in[5];
  const float* b_y0 = (const float*)d_in[6];
  const float* w_x1 = (const float*)d_in[7];
  const float* b_x1 = (const float*)d_in[8];
  const float* w_z1 = (const float*)d_in[9];
  const float* b_z1 = (const float*)d_in[10];
  const float* w_y1 = (const float*)d_in[11];
  const float* b_y1 = (const float*)d_in[12];
  const float* w_last = (const float*)d_in[13];
  (void)in_sizes; (void)n_in; (void)out_size; (void)ws_size;

  uint8_t* wsb = (uint8_t*)d_ws;
  size_t off = 0;
  auto alloc = [&](size_t bytes) -> void* {
    void* p = wsb + off; off += (bytes + 255) & ~(size_t)255; return p;
  };

  const size_t CATB = (size_t)NB*24*4096*8*2;    // 6,291,456 B (chunk-planar f16)
  u16* cat[3][3][2];
  for (int l = 0; l < 3; ++l)
    for (int s = 0; s < 3; ++s) {
      cat[l][s][0] = (u16*)alloc(CATB);
      cat[l][s][1] = (s == 0) ? (u16*)alloc(CATB) : cat[l][s][0];
    }
  const size_t CB = (size_t)NB*HW*32*4;          // 2,097,152 B
  float* cx[3][2]; float* cz[3];
  for (int l = 0; l < 3; ++l) { cx[l][0] = (float*)alloc(CB); cx[l][1] = (float*)alloc(CB); }
  for (int l = 0; l < 3; ++l) cz[l] = (float*)alloc(CB);
  size_t zero_bytes = off;                       // cats + cx + cz

  u16 *wzb[9], *wxb[9];
  for (int c = 0; c < 9; ++c) {
    wzb[c] = (u16*)alloc(75*4096*2);             // 25 taps x 3 kc x 128 co x 32 k
    wxb[c] = (u16*)alloc(27*4096*2);             // 9 taps x 3 kc
  }
  float* predbuf = (float*)alloc((size_t)18*NB*HW*4);

  zero4<<<2048, 256, 0, stream>>>((uint4*)wsb, zero_bytes/16);

  for (int l = 0; l < 3; ++l)
    for (int s = 0; s < 3; ++s) {
      int cell = l*3 + s;
      const float *srcx, *srcz; int cin;
      if (l == 0) { srcx = w_x0 + (size_t)s*128*65*9;  srcz = w_z0 + (size_t)s*128*65*25;  cin = 65; }
      else { int li = (l-1)*3 + s;
             srcx = w_x1 + (size_t)li*128*96*9; srcz = w_z1 + (size_t)li*128*96*25; cin = 96; }
      pack_w<<<(75*4096)/256, 256, 0, stream>>>(srcz, wzb[cell], 25, cin, l==0);
      pack_w<<<(27*4096)/256, 256, 0, stream>>>(srcx, wxb[cell], 9, cin, l==0);
    }

  for (int step = 0; step < 18; ++step) {
    int par = step & 1, npar = par ^ 1;
    frame_fill<<<dim3(64,3), 256, 0, stream>>>(input_seq, predbuf, step,
        cat[0][0][par], cat[0][1][0], cat[0][2][0]);
    for (int l = 0; l < 3; ++l)
      for (int s = 0; s < 3; ++s) {
        int cell = l*3 + s;
        CellArgs A;
        A.cat_in = cat[l][s][(s==0) ? par : 0];
        A.wz = wzb[cell]; A.wx = wxb[cell];
        if (l == 0) { A.bx = b_x0 + s*128; A.bz = b_z0 + s*128; }
        else { int li = (l-1)*3 + s; A.bx = b_x1 + li*128; A.bz = b_z1 + li*128; }
        A.cx_src = (s == 2) ? cx[l][1] : cx[l][0];
        A.cx_dst = (s == 0) ? cx[l][0] : ((s == 1) ? cx[l][1] : nullptr);
        A.cz = cz[l];
        A.hx0 = (s == 0) ? cat[l][1][0] : ((s == 1) ? cat[l][2][0] : nullptr);
        A.hx1 = (s == 0) ? cat[l][0][npar] : nullptr;
        A.hz  = (s < 2) ? cat[l][s+1][0] : cat[l][0][npar];
        A.wy = nullptr; A.by = nullptr; A.y_dst = nullptr;
        A.wl = nullptr; A.pred_out = nullptr; A.final_out = nullptr;
        if (l < 2) {
          if (l == 0) { A.wy = w_y0 + (size_t)s*32*64; A.by = b_y0 + s*32; }
          else        { A.wy = w_y1 + (size_t)s*32*64; A.by = b_y1 + s*32; }
          A.y_dst = cat[l+1][s][(s==0) ? par : 0];
        } else if (s == 2) {
          A.wy = w_y1 + (size_t)5*32*64; A.by = b_y1 + 5*32;
          A.wl = w_last;
          A.pred_out = predbuf + (size_t)step*NB*HW;
          A.final_out = (step >= 8) ? ((float*)d_out + (size_t)(step-8)*HW) : nullptr;
        }
        cell_kernel<<<dim3(64, NB), 512, 0, stream>>>(A);
      }
  }
}